// Round 10
// baseline (317.061 us; speedup 1.0000x reference)
//
#include <hip/hip_runtime.h>
#include <hip/hip_bf16.h>

#define LNUM 13
#define FDIM 768
#define SDIM 512
#define BNUM 32
#define H1DIM 512
#define H2DIM 256
#define GA0 992            // R7 anchor apportionment
#define GPAD (GA0 + BNUM)  // 1024 blocks = 4/CU co-resident (guaranteed: 3 waves, 2.3KB LDS)
#define NSTATS (BNUM * 12) // 384 stats blocks after the in-kernel sync

// ---------------- Kernel AS: kA (R7-identical schedule) + fused stats after a
// device-scope grid sync. Block g in [BB[b],BB[b+1]) handles a contiguous s-range
// of batch b, writes partial slot g; then all blocks fence+count; blocks 0..383
// spin (all 1024 co-resident -> no deadlock), then reduce slots into feats.
__global__ __launch_bounds__(192) void kAS(
    const float* __restrict__ x, const int* __restrict__ lengths,
    const float* __restrict__ lw, float* __restrict__ partial,
    float* __restrict__ feats, unsigned int* __restrict__ done) {
  __shared__ int lenS[BNUM];
  __shared__ int BB[BNUM + 1];
  __shared__ float wS[LNUM];
  __shared__ float rs[3][64], rq[3][64];
  const int tid = threadIdx.x;
  const int g = blockIdx.x;

  if (tid < BNUM) lenS[tid] = lengths[tid];
  __syncthreads();
  if (tid == 0) {
    int T = 0;
    #pragma unroll
    for (int b = 0; b < BNUM; ++b) T += lenS[b];
    int acc = 0; BB[0] = 0;
    #pragma unroll
    for (int b = 0; b < BNUM; ++b) {
      int nb = (T > 0 && lenS[b] > 0) ? (lenS[b] * GA0 + T - 1) / T : 0;
      acc += nb; BB[b + 1] = acc;
    }
    float m = lw[0];
    #pragma unroll
    for (int l = 1; l < LNUM; ++l) m = fmaxf(m, lw[l]);
    float e[LNUM]; float s = 0.f;
    #pragma unroll
    for (int l = 0; l < LNUM; ++l) { e[l] = expf(lw[l] - m); s += e[l]; }
    #pragma unroll
    for (int l = 0; l < LNUM; ++l) wS[l] = e[l] / s;
  }
  __syncthreads();

  // ---- phase 1: partial sum/sumsq (byte-identical schedule to R7 kA)
  if (g < BB[BNUM]) {
    int lo = 0, hi = BNUM;
    while (hi - lo > 1) { int mid = (lo + hi) >> 1; if (g >= BB[mid]) lo = mid; else hi = mid; }
    const int b   = lo;
    const int i   = g - BB[b];
    const int n   = BB[b + 1] - BB[b];
    const int len = lenS[b];
    const int base = len / n, rem = len % n;
    const int s0 = i * base + min(i, rem);
    const int cnt = base + (i < rem ? 1 : 0);

    float4 sum = make_float4(0.f, 0.f, 0.f, 0.f);
    float4 sq  = make_float4(0.f, 0.f, 0.f, 0.f);
    const float* xb = x + (size_t)b * SDIM * (LNUM * FDIM) + (size_t)tid * 4;

    for (int s = s0; s < s0 + cnt; ++s) {
      const float* xs = xb + (size_t)s * (LNUM * FDIM);
      float4 word = make_float4(0.f, 0.f, 0.f, 0.f);
      #pragma unroll
      for (int l = 0; l < LNUM; ++l) {
        float4 v = *reinterpret_cast<const float4*>(xs + l * FDIM);
        const float wl = wS[l];
        word.x = fmaf(wl, v.x, word.x);
        word.y = fmaf(wl, v.y, word.y);
        word.z = fmaf(wl, v.z, word.z);
        word.w = fmaf(wl, v.w, word.w);
      }
      sum.x += word.x; sum.y += word.y; sum.z += word.z; sum.w += word.w;
      sq.x = fmaf(word.x, word.x, sq.x);
      sq.y = fmaf(word.y, word.y, sq.y);
      sq.z = fmaf(word.z, word.z, sq.z);
      sq.w = fmaf(word.w, word.w, sq.w);
    }

    float* p = partial + (size_t)g * (2 * FDIM) + (size_t)tid * 4;
    *reinterpret_cast<float4*>(p) = sum;
    *reinterpret_cast<float4*>(p + FDIM) = sq;
  }

  // ---- device-scope publish + count
  __threadfence();
  __syncthreads();
  if (tid == 0)
    __hip_atomic_fetch_add(done, 1u, __ATOMIC_RELEASE, __HIP_MEMORY_SCOPE_AGENT);
  if (g >= NSTATS) return;

  // ---- phase 2 (blocks 0..383): wait for all partials, then stats
  if (tid == 0) {
    while (__hip_atomic_load(done, __ATOMIC_ACQUIRE, __HIP_MEMORY_SCOPE_AGENT) < GPAD)
      __builtin_amdgcn_s_sleep(8);
  }
  __syncthreads();
  __threadfence();

  const int b  = g / 12;
  const int cg = g % 12;
  const int cl = tid & 63;
  const int k  = tid >> 6;            // 0..2
  const int f  = cg * 64 + cl;

  const int cBeg = BB[b], cEnd = BB[b + 1];
  float ms = 0.f, mq = 0.f;
  for (int cc = cBeg + k; cc < cEnd; cc += 3) {
    const float* p = partial + (size_t)cc * (2 * FDIM);
    // agent-scope loads: bypass potentially-stale caches (prev replay touched same lines)
    ms += __hip_atomic_load(&p[f],        __ATOMIC_RELAXED, __HIP_MEMORY_SCOPE_AGENT);
    mq += __hip_atomic_load(&p[FDIM + f], __ATOMIC_RELAXED, __HIP_MEMORY_SCOPE_AGENT);
  }
  rs[k][cl] = ms; rq[k][cl] = mq;
  __syncthreads();

  if (tid < 64) {
    ms = rs[0][cl] + rs[1][cl] + rs[2][cl];
    mq = rq[0][cl] + rq[1][cl] + rq[2][cl];
    const int n = lenS[b];
    const float fn = (float)n;
    const float mean = ms / fmaxf(fn, 1.f);
    const float var = (mq - fn * mean * mean) / fmaxf(fn - 1.f, 1.f);
    const float sd = (n > 1) ? sqrtf(fmaxf(var, 0.f)) : 0.f;
    feats[(size_t)b * 2 * FDIM + f] = mean;
    feats[(size_t)b * 2 * FDIM + FDIM + f] = sd;
  }
}

// ---------------- Kernel C: h1 = relu(feats @ W1 + b1)   (R7-identical)
__global__ __launch_bounds__(512) void kFC1(
    const float* __restrict__ feats, const float* __restrict__ W1,
    const float* __restrict__ b1, float* __restrict__ h1) {
  const int b  = blockIdx.x >> 2;
  const int jt = blockIdx.x & 3;
  const int t  = threadIdx.x;
  const int jl = t & 127;
  const int kh = t >> 7;              // 0..3
  const int j  = jt * 128 + jl;

  __shared__ float fs[2 * FDIM];      // 6 KB
  __shared__ float red[4][128];       // 2 KB

  for (int i = t; i < 2 * FDIM; i += 512)
    fs[i] = feats[(size_t)b * 2 * FDIM + i];
  __syncthreads();

  const float* wcol = W1 + (size_t)kh * 384 * H1DIM + j;
  const float* fk = fs + kh * 384;
  float acc = 0.f;
  #pragma unroll 16
  for (int i = 0; i < 384; ++i)
    acc = fmaf(fk[i], wcol[(size_t)i * H1DIM], acc);
  red[kh][jl] = acc;
  __syncthreads();

  if (t < 128) {
    float a = red[0][t] + red[1][t] + red[2][t] + red[3][t] + b1[jt * 128 + t];
    h1[(size_t)b * H1DIM + jt * 128 + t] = fmaxf(a, 0.f);
  }
}

// ---------------- Kernel D: h2 = relu(h1 @ W2 + b2); out = h2 @ W3 + b3  (R7-identical)
__global__ __launch_bounds__(512) void kFC23(
    const float* __restrict__ h1, const float* __restrict__ W2,
    const float* __restrict__ b2, const float* __restrict__ W3,
    const float* __restrict__ b3, float* __restrict__ out) {
  const int b = blockIdx.x;
  const int t = threadIdx.x;
  const int jl = t & 255;
  const int kh = t >> 8;              // 0..1

  __shared__ float hs[H1DIM];         // 2 KB
  __shared__ float red[2 * H2DIM];    // 2 KB
  __shared__ float wred[8];

  if (t < H1DIM) hs[t] = h1[(size_t)b * H1DIM + t];
  __syncthreads();

  const float* wcol = W2 + (size_t)kh * 256 * H2DIM + jl;
  const float* hk = hs + kh * 256;
  float acc = 0.f;
  #pragma unroll 16
  for (int i = 0; i < 256; ++i)
    acc = fmaf(hk[i], wcol[(size_t)i * H2DIM], acc);
  red[kh * H2DIM + jl] = acc;
  __syncthreads();

  float v = 0.f;
  if (t < H2DIM) {
    const float h2 = fmaxf(red[t] + red[H2DIM + t] + b2[t], 0.f);
    v = h2 * W3[t];
  }
  #pragma unroll
  for (int off = 32; off > 0; off >>= 1) v += __shfl_down(v, off, 64);
  if ((t & 63) == 0) wred[t >> 6] = v;
  __syncthreads();
  if (t == 0) {
    float r = b3[0];
    #pragma unroll
    for (int i = 0; i < 8; ++i) r += wred[i];
    out[b] = r;
  }
}

extern "C" void kernel_launch(void* const* d_in, const int* in_sizes, int n_in,
                              void* d_out, int out_size, void* d_ws, size_t ws_size,
                              hipStream_t stream) {
  const float* x       = (const float*)d_in[0];
  const int*   lengths = (const int*)  d_in[1];
  const float* lw      = (const float*)d_in[2];
  const float* W1      = (const float*)d_in[3];
  const float* b1      = (const float*)d_in[4];
  const float* W2      = (const float*)d_in[5];
  const float* b2      = (const float*)d_in[6];
  const float* W3      = (const float*)d_in[7];
  const float* b3      = (const float*)d_in[8];
  float* out = (float*)d_out;

  float* partial = (float*)d_ws;                              // GPAD * 2F floats (6.3 MB)
  float* feats   = partial + (size_t)GPAD * 2 * FDIM;         // B * 2F
  float* h1      = feats + (size_t)BNUM * 2 * FDIM;           // B * H1
  unsigned int* done = (unsigned int*)(h1 + (size_t)BNUM * H1DIM);

  hipMemsetAsync(done, 0, sizeof(unsigned int), stream);
  kAS<<<dim3(GPAD), dim3(192), 0, stream>>>(x, lengths, lw, partial, feats, done);
  kFC1<<<dim3(BNUM * 4), dim3(512), 0, stream>>>(feats, W1, b1, h1);
  kFC23<<<dim3(BNUM), dim3(512), 0, stream>>>(h1, W2, b2, W3, b3, out);
}

// Round 11
// 87.131 us; speedup vs baseline: 3.6389x; 3.6389x over previous
//
#include <hip/hip_runtime.h>
#include <hip/hip_bf16.h>

#define LNUM 13
#define FDIM 768
#define SDIM 512
#define BNUM 32
#define H1DIM 512
#define H2DIM 256
#define GA0 496            // target blocks for apportionment
#define GPAD (GA0 + 16)    // 512 launched blocks = 2 blocks/CU (12 waves/CU, same as R7)

// Deterministic apportionment: n_b = ceil(len_b * GA0 / T), BB = prefix(n_b).
// Computed identically (integer math) in kA and kStats.

// ---------------- Kernel A: block g handles a contiguous s-range of batch b;
// 384 thr = 2 s-groups of 192 (each covers all 768 f as float4); halves combined
// in LDS, written to partial slot g. Long ~660KB streams, CU skew <= ~1.04.
__global__ __launch_bounds__(384) void kA_partials(
    const float* __restrict__ x, const int* __restrict__ lengths,
    const float* __restrict__ lw, float* __restrict__ partial) {
  __shared__ int lenS[BNUM];
  __shared__ int BB[BNUM + 1];
  __shared__ float wS[LNUM];
  __shared__ float comb[2 * FDIM];     // half-1 sum[768] + sq[768]
  const int tid = threadIdx.x;
  const int h  = tid / 192;            // s-subgroup 0/1
  const int tl = tid % 192;            // covers f = 4*tl .. 4*tl+3

  if (tid < BNUM) lenS[tid] = lengths[tid];
  __syncthreads();
  if (tid == 0) {
    int T = 0;
    #pragma unroll
    for (int b = 0; b < BNUM; ++b) T += lenS[b];
    int acc = 0; BB[0] = 0;
    #pragma unroll
    for (int b = 0; b < BNUM; ++b) {
      int nb = (T > 0 && lenS[b] > 0) ? (lenS[b] * GA0 + T - 1) / T : 0;
      acc += nb; BB[b + 1] = acc;
    }
    float m = lw[0];
    #pragma unroll
    for (int l = 1; l < LNUM; ++l) m = fmaxf(m, lw[l]);
    float e[LNUM]; float s = 0.f;
    #pragma unroll
    for (int l = 0; l < LNUM; ++l) { e[l] = expf(lw[l] - m); s += e[l]; }
    #pragma unroll
    for (int l = 0; l < LNUM; ++l) wS[l] = e[l] / s;
  }
  __syncthreads();

  const int g = blockIdx.x;
  if (g >= BB[BNUM]) return;           // idle block; its slot is never read

  int lo = 0, hi = BNUM;
  while (hi - lo > 1) { int mid = (lo + hi) >> 1; if (g >= BB[mid]) lo = mid; else hi = mid; }
  const int b   = lo;
  const int i   = g - BB[b];
  const int n   = BB[b + 1] - BB[b];
  const int len = lenS[b];
  const int base = len / n, rem = len % n;
  const int s0 = i * base + min(i, rem);
  const int cnt = base + (i < rem ? 1 : 0);

  float4 sum = make_float4(0.f, 0.f, 0.f, 0.f);
  float4 sq  = make_float4(0.f, 0.f, 0.f, 0.f);
  const float* xb = x + (size_t)b * SDIM * (LNUM * FDIM) + (size_t)tl * 4;

  for (int s = s0 + h; s < s0 + cnt; s += 2) {
    const float* xs = xb + (size_t)s * (LNUM * FDIM);
    float4 word = make_float4(0.f, 0.f, 0.f, 0.f);
    #pragma unroll
    for (int l = 0; l < LNUM; ++l) {
      float4 v = *reinterpret_cast<const float4*>(xs + l * FDIM);
      const float wl = wS[l];
      word.x = fmaf(wl, v.x, word.x);
      word.y = fmaf(wl, v.y, word.y);
      word.z = fmaf(wl, v.z, word.z);
      word.w = fmaf(wl, v.w, word.w);
    }
    sum.x += word.x; sum.y += word.y; sum.z += word.z; sum.w += word.w;
    sq.x = fmaf(word.x, word.x, sq.x);
    sq.y = fmaf(word.y, word.y, sq.y);
    sq.z = fmaf(word.z, word.z, sq.z);
    sq.w = fmaf(word.w, word.w, sq.w);
  }

  // combine halves (fixed order: half0 += half1) and write slot g
  if (h == 1) {
    *reinterpret_cast<float4*>(&comb[4 * tl]) = sum;
    *reinterpret_cast<float4*>(&comb[FDIM + 4 * tl]) = sq;
  }
  __syncthreads();
  if (h == 0) {
    float4 s1 = *reinterpret_cast<const float4*>(&comb[4 * tl]);
    float4 q1 = *reinterpret_cast<const float4*>(&comb[FDIM + 4 * tl]);
    sum.x += s1.x; sum.y += s1.y; sum.z += s1.z; sum.w += s1.w;
    sq.x  += q1.x; sq.y  += q1.y; sq.z  += q1.z; sq.w  += q1.w;
    float* p = partial + (size_t)g * (2 * FDIM) + (size_t)tl * 4;
    *reinterpret_cast<float4*>(p) = sum;        // zeros if cnt==0 (slot is read)
    *reinterpret_cast<float4*>(p + FDIM) = sq;
  }
}

// ---------------- Kernel S: reduce slots [BB[b], BB[b+1]) -> feats [B, 2F]
// grid = B * 12 (col-groups of 64), 256 thr = 64 cols x 4 slot-slices, LDS reduce
__global__ __launch_bounds__(256) void kStats(
    const float* __restrict__ partial, const int* __restrict__ lengths,
    float* __restrict__ feats) {
  const int b  = blockIdx.x / 12;
  const int cg = blockIdx.x % 12;
  const int cl = threadIdx.x & 63;
  const int k  = threadIdx.x >> 6;      // 0..3
  const int f  = cg * 64 + cl;

  __shared__ int lenS[BNUM];
  __shared__ int BB[BNUM + 1];
  if (threadIdx.x < BNUM) lenS[threadIdx.x] = lengths[threadIdx.x];
  __syncthreads();
  if (threadIdx.x == 0) {
    int T = 0;
    #pragma unroll
    for (int bb = 0; bb < BNUM; ++bb) T += lenS[bb];
    int acc = 0; BB[0] = 0;
    #pragma unroll
    for (int bb = 0; bb < BNUM; ++bb) {
      int nb = (T > 0 && lenS[bb] > 0) ? (lenS[bb] * GA0 + T - 1) / T : 0;
      acc += nb; BB[bb + 1] = acc;
    }
  }
  __syncthreads();

  const int cBeg = BB[b], cEnd = BB[b + 1];
  float ms = 0.f, mq = 0.f;
  for (int cc = cBeg + k; cc < cEnd; cc += 4) {
    const float* p = partial + (size_t)cc * (2 * FDIM);
    ms += p[f];
    mq += p[FDIM + f];
  }
  __shared__ float rs[4][64], rq[4][64];
  rs[k][cl] = ms; rq[k][cl] = mq;
  __syncthreads();

  if (threadIdx.x < 64) {
    ms = rs[0][cl] + rs[1][cl] + rs[2][cl] + rs[3][cl];
    mq = rq[0][cl] + rq[1][cl] + rq[2][cl] + rq[3][cl];
    const int n = lenS[b];
    const float fn = (float)n;
    const float mean = ms / fmaxf(fn, 1.f);
    const float var = (mq - fn * mean * mean) / fmaxf(fn - 1.f, 1.f);
    const float sd = (n > 1) ? sqrtf(fmaxf(var, 0.f)) : 0.f;
    feats[(size_t)b * 2 * FDIM + f] = mean;
    feats[(size_t)b * 2 * FDIM + FDIM + f] = sd;
  }
}

// ---------------- Kernel C: h1 = relu(feats @ W1 + b1)   (R7-identical)
__global__ __launch_bounds__(512) void kFC1(
    const float* __restrict__ feats, const float* __restrict__ W1,
    const float* __restrict__ b1, float* __restrict__ h1) {
  const int b  = blockIdx.x >> 2;
  const int jt = blockIdx.x & 3;
  const int t  = threadIdx.x;
  const int jl = t & 127;
  const int kh = t >> 7;              // 0..3
  const int j  = jt * 128 + jl;

  __shared__ float fs[2 * FDIM];      // 6 KB
  __shared__ float red[4][128];       // 2 KB

  for (int i = t; i < 2 * FDIM; i += 512)
    fs[i] = feats[(size_t)b * 2 * FDIM + i];
  __syncthreads();

  const float* wcol = W1 + (size_t)kh * 384 * H1DIM + j;
  const float* fk = fs + kh * 384;
  float acc = 0.f;
  #pragma unroll 16
  for (int i = 0; i < 384; ++i)
    acc = fmaf(fk[i], wcol[(size_t)i * H1DIM], acc);
  red[kh][jl] = acc;
  __syncthreads();

  if (t < 128) {
    float a = red[0][t] + red[1][t] + red[2][t] + red[3][t] + b1[jt * 128 + t];
    h1[(size_t)b * H1DIM + jt * 128 + t] = fmaxf(a, 0.f);
  }
}

// ---------------- Kernel D: h2 = relu(h1 @ W2 + b2); out = h2 @ W3 + b3  (R7-identical)
__global__ __launch_bounds__(512) void kFC23(
    const float* __restrict__ h1, const float* __restrict__ W2,
    const float* __restrict__ b2, const float* __restrict__ W3,
    const float* __restrict__ b3, float* __restrict__ out) {
  const int b = blockIdx.x;
  const int t = threadIdx.x;
  const int jl = t & 255;
  const int kh = t >> 8;              // 0..1

  __shared__ float hs[H1DIM];         // 2 KB
  __shared__ float red[2 * H2DIM];    // 2 KB
  __shared__ float wred[8];

  if (t < H1DIM) hs[t] = h1[(size_t)b * H1DIM + t];
  __syncthreads();

  const float* wcol = W2 + (size_t)kh * 256 * H2DIM + jl;
  const float* hk = hs + kh * 256;
  float acc = 0.f;
  #pragma unroll 16
  for (int i = 0; i < 256; ++i)
    acc = fmaf(hk[i], wcol[(size_t)i * H2DIM], acc);
  red[kh * H2DIM + jl] = acc;
  __syncthreads();

  float v = 0.f;
  if (t < H2DIM) {
    const float h2 = fmaxf(red[t] + red[H2DIM + t] + b2[t], 0.f);
    v = h2 * W3[t];
  }
  #pragma unroll
  for (int off = 32; off > 0; off >>= 1) v += __shfl_down(v, off, 64);
  if ((t & 63) == 0) wred[t >> 6] = v;
  __syncthreads();
  if (t == 0) {
    float r = b3[0];
    #pragma unroll
    for (int i = 0; i < 8; ++i) r += wred[i];
    out[b] = r;
  }
}

extern "C" void kernel_launch(void* const* d_in, const int* in_sizes, int n_in,
                              void* d_out, int out_size, void* d_ws, size_t ws_size,
                              hipStream_t stream) {
  const float* x       = (const float*)d_in[0];
  const int*   lengths = (const int*)  d_in[1];
  const float* lw      = (const float*)d_in[2];
  const float* W1      = (const float*)d_in[3];
  const float* b1      = (const float*)d_in[4];
  const float* W2      = (const float*)d_in[5];
  const float* b2      = (const float*)d_in[6];
  const float* W3      = (const float*)d_in[7];
  const float* b3      = (const float*)d_in[8];
  float* out = (float*)d_out;

  float* partial = (float*)d_ws;                              // GPAD * 2F floats (3.1 MB)
  float* feats   = partial + (size_t)GPAD * 2 * FDIM;         // B * 2F
  float* h1      = feats + (size_t)BNUM * 2 * FDIM;           // B * H1

  kA_partials<<<dim3(GPAD), dim3(384), 0, stream>>>(x, lengths, lw, partial);
  kStats<<<dim3(BNUM * 12), dim3(256), 0, stream>>>(partial, lengths, feats);
  kFC1<<<dim3(BNUM * 4), dim3(512), 0, stream>>>(feats, W1, b1, h1);
  kFC23<<<dim3(BNUM), dim3(512), 0, stream>>>(h1, W2, b2, W3, b3, out);
}

// Round 13
// 78.587 us; speedup vs baseline: 4.0345x; 1.1087x over previous
//
#include <hip/hip_runtime.h>
#include <hip/hip_bf16.h>

#define LNUM 13
#define FDIM 768
#define SDIM 512
#define BNUM 32
#define H1DIM 512
#define H2DIM 256
#define GA0 496            // target blocks for apportionment
#define GPAD (GA0 + 16)    // 512 launched blocks = 2 blocks/CU (12 waves/CU)

typedef float f32x4 __attribute__((ext_vector_type(4)));  // native vec for nt-load

// Deterministic apportionment: n_b = ceil(len_b * GA0 / T), BB = prefix(n_b).
// Computed identically (integer math) in kA and kStats.

// ---------------- Kernel A: block g handles a contiguous s-range of batch b;
// 384 thr = 2 s-groups of 192; halves combined in LDS, written to slot g.
// ONLY change vs R11: x loads are non-temporal (bypass L2/L3 allocation --
// x is read exactly once; allocate+evict at 654MB scale is pure overhead).
__global__ __launch_bounds__(384) void kA_partials(
    const float* __restrict__ x, const int* __restrict__ lengths,
    const float* __restrict__ lw, float* __restrict__ partial) {
  __shared__ int lenS[BNUM];
  __shared__ int BB[BNUM + 1];
  __shared__ float wS[LNUM];
  __shared__ float comb[2 * FDIM];     // half-1 sum[768] + sq[768]
  const int tid = threadIdx.x;
  const int h  = tid / 192;            // s-subgroup 0/1
  const int tl = tid % 192;            // covers f = 4*tl .. 4*tl+3

  if (tid < BNUM) lenS[tid] = lengths[tid];
  __syncthreads();
  if (tid == 0) {
    int T = 0;
    #pragma unroll
    for (int b = 0; b < BNUM; ++b) T += lenS[b];
    int acc = 0; BB[0] = 0;
    #pragma unroll
    for (int b = 0; b < BNUM; ++b) {
      int nb = (T > 0 && lenS[b] > 0) ? (lenS[b] * GA0 + T - 1) / T : 0;
      acc += nb; BB[b + 1] = acc;
    }
    float m = lw[0];
    #pragma unroll
    for (int l = 1; l < LNUM; ++l) m = fmaxf(m, lw[l]);
    float e[LNUM]; float s = 0.f;
    #pragma unroll
    for (int l = 0; l < LNUM; ++l) { e[l] = expf(lw[l] - m); s += e[l]; }
    #pragma unroll
    for (int l = 0; l < LNUM; ++l) wS[l] = e[l] / s;
  }
  __syncthreads();

  const int g = blockIdx.x;
  if (g >= BB[BNUM]) return;           // idle block; its slot is never read

  int lo = 0, hi = BNUM;
  while (hi - lo > 1) { int mid = (lo + hi) >> 1; if (g >= BB[mid]) lo = mid; else hi = mid; }
  const int b   = lo;
  const int i   = g - BB[b];
  const int n   = BB[b + 1] - BB[b];
  const int len = lenS[b];
  const int base = len / n, rem = len % n;
  const int s0 = i * base + min(i, rem);
  const int cnt = base + (i < rem ? 1 : 0);

  float4 sum = make_float4(0.f, 0.f, 0.f, 0.f);
  float4 sq  = make_float4(0.f, 0.f, 0.f, 0.f);
  const float* xb = x + (size_t)b * SDIM * (LNUM * FDIM) + (size_t)tl * 4;

  for (int s = s0 + h; s < s0 + cnt; s += 2) {
    const float* xs = xb + (size_t)s * (LNUM * FDIM);
    float4 word = make_float4(0.f, 0.f, 0.f, 0.f);
    #pragma unroll
    for (int l = 0; l < LNUM; ++l) {
      f32x4 v = __builtin_nontemporal_load(
          reinterpret_cast<const f32x4*>(xs + l * FDIM));
      const float wl = wS[l];
      word.x = fmaf(wl, v.x, word.x);
      word.y = fmaf(wl, v.y, word.y);
      word.z = fmaf(wl, v.z, word.z);
      word.w = fmaf(wl, v.w, word.w);
    }
    sum.x += word.x; sum.y += word.y; sum.z += word.z; sum.w += word.w;
    sq.x = fmaf(word.x, word.x, sq.x);
    sq.y = fmaf(word.y, word.y, sq.y);
    sq.z = fmaf(word.z, word.z, sq.z);
    sq.w = fmaf(word.w, word.w, sq.w);
  }

  // combine halves (fixed order: half0 += half1) and write slot g
  if (h == 1) {
    *reinterpret_cast<float4*>(&comb[4 * tl]) = sum;
    *reinterpret_cast<float4*>(&comb[FDIM + 4 * tl]) = sq;
  }
  __syncthreads();
  if (h == 0) {
    float4 s1 = *reinterpret_cast<const float4*>(&comb[4 * tl]);
    float4 q1 = *reinterpret_cast<const float4*>(&comb[FDIM + 4 * tl]);
    sum.x += s1.x; sum.y += s1.y; sum.z += s1.z; sum.w += s1.w;
    sq.x  += q1.x; sq.y  += q1.y; sq.z  += q1.z; sq.w  += q1.w;
    float* p = partial + (size_t)g * (2 * FDIM) + (size_t)tl * 4;
    *reinterpret_cast<float4*>(p) = sum;        // zeros if cnt==0 (slot is read)
    *reinterpret_cast<float4*>(p + FDIM) = sq;
  }
}

// ---------------- Kernel S: reduce slots [BB[b], BB[b+1]) -> feats [B, 2F]
// grid = B * 12 (col-groups of 64), 256 thr = 64 cols x 4 slot-slices, LDS reduce
__global__ __launch_bounds__(256) void kStats(
    const float* __restrict__ partial, const int* __restrict__ lengths,
    float* __restrict__ feats) {
  const int b  = blockIdx.x / 12;
  const int cg = blockIdx.x % 12;
  const int cl = threadIdx.x & 63;
  const int k  = threadIdx.x >> 6;      // 0..3
  const int f  = cg * 64 + cl;

  __shared__ int lenS[BNUM];
  __shared__ int BB[BNUM + 1];
  if (threadIdx.x < BNUM) lenS[threadIdx.x] = lengths[threadIdx.x];
  __syncthreads();
  if (threadIdx.x == 0) {
    int T = 0;
    #pragma unroll
    for (int bb = 0; bb < BNUM; ++bb) T += lenS[bb];
    int acc = 0; BB[0] = 0;
    #pragma unroll
    for (int bb = 0; bb < BNUM; ++bb) {
      int nb = (T > 0 && lenS[bb] > 0) ? (lenS[bb] * GA0 + T - 1) / T : 0;
      acc += nb; BB[bb + 1] = acc;
    }
  }
  __syncthreads();

  const int cBeg = BB[b], cEnd = BB[b + 1];
  float ms = 0.f, mq = 0.f;
  for (int cc = cBeg + k; cc < cEnd; cc += 4) {
    const float* p = partial + (size_t)cc * (2 * FDIM);
    ms += p[f];
    mq += p[FDIM + f];
  }
  __shared__ float rs[4][64], rq[4][64];
  rs[k][cl] = ms; rq[k][cl] = mq;
  __syncthreads();

  if (threadIdx.x < 64) {
    ms = rs[0][cl] + rs[1][cl] + rs[2][cl] + rs[3][cl];
    mq = rq[0][cl] + rq[1][cl] + rq[2][cl] + rq[3][cl];
    const int n = lenS[b];
    const float fn = (float)n;
    const float mean = ms / fmaxf(fn, 1.f);
    const float var = (mq - fn * mean * mean) / fmaxf(fn - 1.f, 1.f);
    const float sd = (n > 1) ? sqrtf(fmaxf(var, 0.f)) : 0.f;
    feats[(size_t)b * 2 * FDIM + f] = mean;
    feats[(size_t)b * 2 * FDIM + FDIM + f] = sd;
  }
}

// ---------------- Kernel C: h1 = relu(feats @ W1 + b1)   (R7-identical)
__global__ __launch_bounds__(512) void kFC1(
    const float* __restrict__ feats, const float* __restrict__ W1,
    const float* __restrict__ b1, float* __restrict__ h1) {
  const int b  = blockIdx.x >> 2;
  const int jt = blockIdx.x & 3;
  const int t  = threadIdx.x;
  const int jl = t & 127;
  const int kh = t >> 7;              // 0..3
  const int j  = jt * 128 + jl;

  __shared__ float fs[2 * FDIM];      // 6 KB
  __shared__ float red[4][128];       // 2 KB

  for (int i = t; i < 2 * FDIM; i += 512)
    fs[i] = feats[(size_t)b * 2 * FDIM + i];
  __syncthreads();

  const float* wcol = W1 + (size_t)kh * 384 * H1DIM + j;
  const float* fk = fs + kh * 384;
  float acc = 0.f;
  #pragma unroll 16
  for (int i = 0; i < 384; ++i)
    acc = fmaf(fk[i], wcol[(size_t)i * H1DIM], acc);
  red[kh][jl] = acc;
  __syncthreads();

  if (t < 128) {
    float a = red[0][t] + red[1][t] + red[2][t] + red[3][t] + b1[jt * 128 + t];
    h1[(size_t)b * H1DIM + jt * 128 + t] = fmaxf(a, 0.f);
  }
}

// ---------------- Kernel D: h2 = relu(h1 @ W2 + b2); out = h2 @ W3 + b3  (R7-identical)
__global__ __launch_bounds__(512) void kFC23(
    const float* __restrict__ h1, const float* __restrict__ W2,
    const float* __restrict__ b2, const float* __restrict__ W3,
    const float* __restrict__ b3, float* __restrict__ out) {
  const int b = blockIdx.x;
  const int t = threadIdx.x;
  const int jl = t & 255;
  const int kh = t >> 8;              // 0..1

  __shared__ float hs[H1DIM];         // 2 KB
  __shared__ float red[2 * H2DIM];    // 2 KB
  __shared__ float wred[8];

  if (t < H1DIM) hs[t] = h1[(size_t)b * H1DIM + t];
  __syncthreads();

  const float* wcol = W2 + (size_t)kh * 256 * H2DIM + jl;
  const float* hk = hs + kh * 256;
  float acc = 0.f;
  #pragma unroll 16
  for (int i = 0; i < 256; ++i)
    acc = fmaf(hk[i], wcol[(size_t)i * H2DIM], acc);
  red[kh * H2DIM + jl] = acc;
  __syncthreads();

  float v = 0.f;
  if (t < H2DIM) {
    const float h2 = fmaxf(red[t] + red[H2DIM + t] + b2[t], 0.f);
    v = h2 * W3[t];
  }
  #pragma unroll
  for (int off = 32; off > 0; off >>= 1) v += __shfl_down(v, off, 64);
  if ((t & 63) == 0) wred[t >> 6] = v;
  __syncthreads();
  if (t == 0) {
    float r = b3[0];
    #pragma unroll
    for (int i = 0; i < 8; ++i) r += wred[i];
    out[b] = r;
  }
}

extern "C" void kernel_launch(void* const* d_in, const int* in_sizes, int n_in,
                              void* d_out, int out_size, void* d_ws, size_t ws_size,
                              hipStream_t stream) {
  const float* x       = (const float*)d_in[0];
  const int*   lengths = (const int*)  d_in[1];
  const float* lw      = (const float*)d_in[2];
  const float* W1      = (const float*)d_in[3];
  const float* b1      = (const float*)d_in[4];
  const float* W2      = (const float*)d_in[5];
  const float* b2      = (const float*)d_in[6];
  const float* W3      = (const float*)d_in[7];
  const float* b3      = (const float*)d_in[8];
  float* out = (float*)d_out;

  float* partial = (float*)d_ws;                              // GPAD * 2F floats (3.1 MB)
  float* feats   = partial + (size_t)GPAD * 2 * FDIM;         // B * 2F
  float* h1      = feats + (size_t)BNUM * 2 * FDIM;           // B * H1

  kA_partials<<<dim3(GPAD), dim3(384), 0, stream>>>(x, lengths, lw, partial);
  kStats<<<dim3(BNUM * 12), dim3(256), 0, stream>>>(partial, lengths, feats);
  kFC1<<<dim3(BNUM * 4), dim3(512), 0, stream>>>(feats, W1, b1, h1);
  kFC23<<<dim3(BNUM), dim3(512), 0, stream>>>(h1, W2, b2, W3, b3, out);
}